// Round 5
// baseline (127.767 us; speedup 1.0000x reference)
//
#include <hip/hip_runtime.h>

// EKF_v2: B=16384 batches, N=128 particles, DX=5, DZ=2.
// R4 structure (known-good codegen: FETCH 33MB / WRITE 41MB, no scratch)
// + packed-fp32 (v_pk_fma_f32) MLP: h1/layer2/layer3 computed on particle
// PAIRS via ext_vector_type(2) floats (weights broadcast via op_sel).
// One block = 4 batches (512 particles), 128 threads, 4 particles/thread.

#define NBATCH_PER_BLOCK 4

typedef float v2f __attribute__((ext_vector_type(2)));

__device__ __forceinline__ v2f splat2(float x) { v2f r; r.x = x; r.y = x; return r; }

__global__ __launch_bounds__(128) void ekf_fused(
    const float* __restrict__ state_old,  // (B,128,5)
    const float* __restrict__ y_obs,      // (B,128,2)
    const float* __restrict__ encoding,   // (B,128)
    const float* __restrict__ pw1,        // (2,16)
    const float* __restrict__ pb1,        // (16)
    const float* __restrict__ pw2,        // (16,32)
    const float* __restrict__ pb2,        // (32)
    const float* __restrict__ pw3,        // (32,2)
    const float* __restrict__ pb3,        // (2)
    const float* __restrict__ nw1,        // (128,32)
    const float* __restrict__ nb1,        // (32)
    const float* __restrict__ nw2,        // (32,2)
    const float* __restrict__ nb2,        // (2)
    const float* __restrict__ lob,        // (2)
    const float* __restrict__ fob,        // (2)
    float* __restrict__ out)              // (B,128,5)
{
    __shared__ __align__(16) float s_state[NBATCH_PER_BLOCK * 640]; // in, reused as out staging
    __shared__ __align__(16) float s_y[NBATCH_PER_BLOCK * 256];
    __shared__ __align__(16) float s_enc[NBATCH_PER_BLOCK * 128];
    __shared__ __align__(16) float s_pw2t[512]; // transposed: [j][k] = pw2[k][j]
    __shared__ float s_pw1[32];
    __shared__ float s_pb1[16];
    __shared__ float s_pb2[32];
    __shared__ __align__(8) float s_pw3[64];
    __shared__ float s_pb3[2];
    __shared__ float s_nb1[32];
    __shared__ float s_nw2[64];
    __shared__ float s_nb2[2];
    __shared__ float s_bias[4]; // lob0, lob1, fob0, fob1

    const int t = threadIdx.x;
    const int blk = blockIdx.x;
    const int base = blk * NBATCH_PER_BLOCK; // first batch of this block

    // ---- stage inputs (coalesced float4) ----
    {
        const float4* src = (const float4*)(state_old + (size_t)base * 640);
        float4* dst = (float4*)s_state;
        #pragma unroll
        for (int i = t; i < 640; i += 128) dst[i] = src[i];
        const float4* sy = (const float4*)(y_obs + (size_t)base * 256);
        float4* dy = (float4*)s_y;
        #pragma unroll
        for (int i = t; i < 256; i += 128) dy[i] = sy[i];
        const float4* se = (const float4*)(encoding + (size_t)base * 128);
        float4* de = (float4*)s_enc;
        if (t < 128) de[t] = se[t];
    }
    // ---- stage weights ----
    if (t < 32) { s_pw1[t] = pw1[t]; s_pb2[t] = pb2[t]; s_nb1[t] = nb1[t]; }
    if (t < 16) s_pb1[t] = pb1[t];
    if (t < 64) { s_pw3[t] = pw3[t]; s_nw2[t] = nw2[t]; }
    if (t < 2)  { s_pb3[t] = pb3[t]; s_nb2[t] = nb2[t]; s_bias[t] = lob[t]; s_bias[2 + t] = fob[t]; }
    for (int i = t; i < 512; i += 128) { int j = i >> 4, k = i & 15; s_pw2t[i] = pw2[k * 32 + j]; }
    __syncthreads();

    const int g = t >> 5;     // batch within block
    const int j32 = t & 31;   // lane within batch group

    // ---- noise MLP: diag (per batch); 4 independent FMA chains ----
    float diag0, diag1;
    {
        const float* eg = s_enc + g * 128;
        const float* w = nw1 + j32;
        float a0 = 0.0f, a1 = 0.0f, a2 = 0.0f, a3 = 0.0f;
        #pragma unroll 4
        for (int k = 0; k < 128; k += 4) {
            a0 = fmaf(eg[k + 0], w[(k + 0) * 32], a0);
            a1 = fmaf(eg[k + 1], w[(k + 1) * 32], a1);
            a2 = fmaf(eg[k + 2], w[(k + 2) * 32], a2);
            a3 = fmaf(eg[k + 3], w[(k + 3) * 32], a3);
        }
        float acc = ((a0 + a1) + (a2 + a3)) + s_nb1[j32];
        float h = fmaxf(acc, 0.0f);
        float d0 = h * s_nw2[j32 * 2 + 0];
        float d1 = h * s_nw2[j32 * 2 + 1];
        #pragma unroll
        for (int off = 1; off < 32; off <<= 1) {
            d0 += __shfl_xor(d0, off, 64);
            d1 += __shfl_xor(d1, off, 64);
        }
        d0 += s_nb2[0]; d1 += s_nb2[1];
        float e0 = d0 + s_bias[0], e1 = d1 + s_bias[1];
        diag0 = fmaf(e0, e0, s_bias[2]);
        diag1 = fmaf(e1, e1, s_bias[3]);
    }

    // ---- process model: 4 particles/thread, packed in pairs (m=2pi, 2pi+1) ----
    float xp[4][5];
    v2f h1p[2][16];
    #pragma unroll
    for (int pi = 0; pi < 2; ++pi) {
        const int m0 = 2 * pi, m1 = 2 * pi + 1;
        const float* sA = s_state + g * 640 + (j32 + 32 * m0) * 5;
        const float* sB = s_state + g * 640 + (j32 + 32 * m1) * 5;
        float vA = sA[3], tdA = sA[4];
        float vB = sB[3], tdB = sB[4];
        float thA = sA[2] + tdA;
        float thB = sB[2] + tdB;
        xp[m0][0] = fmaf(vA, __sinf(thA), sA[0]);
        xp[m0][1] = fmaf(vA, __cosf(thA), sA[1]);
        xp[m0][2] = thA; xp[m0][3] = vA; xp[m0][4] = tdA;
        xp[m1][0] = fmaf(vB, __sinf(thB), sB[0]);
        xp[m1][1] = fmaf(vB, __cosf(thB), sB[1]);
        xp[m1][2] = thB; xp[m1][3] = vB; xp[m1][4] = tdB;
        v2f vv; vv.x = vA; vv.y = vB;
        v2f tdv; tdv.x = tdA; tdv.y = tdB;
        #pragma unroll
        for (int q = 0; q < 16; ++q) {
            v2f tmp = __builtin_elementwise_fma(tdv, splat2(s_pw1[16 + q]), splat2(s_pb1[q]));
            v2f h = __builtin_elementwise_fma(vv, splat2(s_pw1[q]), tmp);
            h1p[pi][q] = __builtin_elementwise_max(h, splat2(0.0f));
        }
    }

    // ---- layers 2+3 fused, packed: per j, 2 pair-accumulators ----
    v2f o3p[2], o4p[2];
    o3p[0] = splat2(0.0f); o3p[1] = splat2(0.0f);
    o4p[0] = splat2(0.0f); o4p[1] = splat2(0.0f);
    const float4* w2v = (const float4*)s_pw2t;
    const float2* pw3v = (const float2*)s_pw3;
    #pragma unroll
    for (int j = 0; j < 32; ++j) {
        v2f acc0 = splat2(s_pb2[j]);
        v2f acc1 = acc0;
        #pragma unroll
        for (int q = 0; q < 4; ++q) {
            float4 w = w2v[j * 4 + q];
            acc0 = __builtin_elementwise_fma(h1p[0][4 * q + 0], splat2(w.x), acc0);
            acc0 = __builtin_elementwise_fma(h1p[0][4 * q + 1], splat2(w.y), acc0);
            acc0 = __builtin_elementwise_fma(h1p[0][4 * q + 2], splat2(w.z), acc0);
            acc0 = __builtin_elementwise_fma(h1p[0][4 * q + 3], splat2(w.w), acc0);
            acc1 = __builtin_elementwise_fma(h1p[1][4 * q + 0], splat2(w.x), acc1);
            acc1 = __builtin_elementwise_fma(h1p[1][4 * q + 1], splat2(w.y), acc1);
            acc1 = __builtin_elementwise_fma(h1p[1][4 * q + 2], splat2(w.z), acc1);
            acc1 = __builtin_elementwise_fma(h1p[1][4 * q + 3], splat2(w.w), acc1);
        }
        float2 w3 = pw3v[j];
        v2f r0 = __builtin_elementwise_max(acc0, splat2(0.0f));
        v2f r1 = __builtin_elementwise_max(acc1, splat2(0.0f));
        o3p[0] = __builtin_elementwise_fma(r0, splat2(w3.x), o3p[0]);
        o4p[0] = __builtin_elementwise_fma(r0, splat2(w3.y), o4p[0]);
        o3p[1] = __builtin_elementwise_fma(r1, splat2(w3.x), o3p[1]);
        o4p[1] = __builtin_elementwise_fma(r1, splat2(w3.y), o4p[1]);
    }
    xp[0][3] += o3p[0].x + s_pb3[0];
    xp[1][3] += o3p[0].y + s_pb3[0];
    xp[2][3] += o3p[1].x + s_pb3[0];
    xp[3][3] += o3p[1].y + s_pb3[0];
    xp[0][4] += o4p[0].x + s_pb3[1];
    xp[1][4] += o4p[0].y + s_pb3[1];
    xp[2][4] += o4p[1].x + s_pb3[1];
    xp[3][4] += o4p[1].y + s_pb3[1];

    // ---- per-batch means (butterfly over 32 lanes; all lanes identical) ----
    float mean[5];
    #pragma unroll
    for (int i = 0; i < 5; ++i) {
        float ps = (xp[0][i] + xp[1][i]) + (xp[2][i] + xp[3][i]);
        #pragma unroll
        for (int off = 1; off < 32; off <<= 1) ps += __shfl_xor(ps, off, 64);
        mean[i] = ps * 0.0078125f; // /128 exact
    }

    float A[4][5];
    #pragma unroll
    for (int m = 0; m < 4; ++m)
        #pragma unroll
        for (int i = 0; i < 5; ++i) A[m][i] = xp[m][i] - mean[i];

    // ---- cross-moments S[i][z] = sum_n A[n][i]*A[n][3+z] ----
    float S[5][2];
    #pragma unroll
    for (int i = 0; i < 5; ++i) {
        #pragma unroll
        for (int z = 0; z < 2; ++z) {
            float ps = (A[0][i] * A[0][3 + z] + A[1][i] * A[1][3 + z])
                     + (A[2][i] * A[2][3 + z] + A[3][i] * A[3][3 + z]);
            #pragma unroll
            for (int off = 1; off < 32; off <<= 1) ps += __shfl_xor(ps, off, 64);
            S[i][z] = ps;
        }
    }

    // ---- 2x2 solve: Kt = Pzz^{-1} @ Pxz^T ----
    const float inv_denom = 1.0f / 127.0f;
    float p00 = fmaf(S[3][0], inv_denom, diag0);
    float p01 = S[3][1] * inv_denom;
    float p10 = S[4][0] * inv_denom;
    float p11 = fmaf(S[4][1], inv_denom, diag1);
    float det = p00 * p11 - p01 * p10;
    float rdet = 1.0f / det;
    float Kt0[5], Kt1[5];
    #pragma unroll
    for (int i = 0; i < 5; ++i) {
        float b0 = S[i][0] * inv_denom; // Pxz[i][0]
        float b1 = S[i][1] * inv_denom; // Pxz[i][1]
        Kt0[i] = (p11 * b0 - p01 * b1) * rdet;
        Kt1[i] = (p00 * b1 - p10 * b0) * rdet;
    }

    // ---- Kalman update; stage output in s_state (each thread owns its slots) ----
    __syncthreads(); // all reads of s_state done before overwrite
    #pragma unroll
    for (int m = 0; m < 4; ++m) {
        const float* yy = s_y + g * 256 + (j32 + 32 * m) * 2;
        float i0 = yy[0] - xp[m][3];
        float i1 = yy[1] - xp[m][4];
        float* o = s_state + g * 640 + (j32 + 32 * m) * 5;
        #pragma unroll
        for (int i = 0; i < 5; ++i)
            o[i] = xp[m][i] + i0 * Kt0[i] + i1 * Kt1[i];
    }
    __syncthreads();
    {
        const float4* src = (const float4*)s_state;
        float4* dst = (float4*)(out + (size_t)base * 640);
        #pragma unroll
        for (int i = t; i < 640; i += 128) dst[i] = src[i];
    }
}

extern "C" void kernel_launch(void* const* d_in, const int* in_sizes, int n_in,
                              void* d_out, int out_size, void* d_ws, size_t ws_size,
                              hipStream_t stream) {
    const float* state_old = (const float*)d_in[0];
    const float* y_obs     = (const float*)d_in[1];
    const float* encoding  = (const float*)d_in[2];
    const float* pw1 = (const float*)d_in[3];
    const float* pb1 = (const float*)d_in[4];
    const float* pw2 = (const float*)d_in[5];
    const float* pb2 = (const float*)d_in[6];
    const float* pw3 = (const float*)d_in[7];
    const float* pb3 = (const float*)d_in[8];
    const float* nw1 = (const float*)d_in[9];
    const float* nb1 = (const float*)d_in[10];
    const float* nw2 = (const float*)d_in[11];
    const float* nb2 = (const float*)d_in[12];
    const float* lob = (const float*)d_in[13];
    const float* fob = (const float*)d_in[14];
    float* out = (float*)d_out;

    const int B = 16384;
    dim3 grid(B / NBATCH_PER_BLOCK);
    dim3 block(128);
    hipLaunchKernelGGL(ekf_fused, grid, block, 0, stream,
                       state_old, y_obs, encoding,
                       pw1, pb1, pw2, pb2, pw3, pb3,
                       nw1, nb1, nw2, nb2, lob, fob, out);
}

// Round 6
// 72.227 us; speedup vs baseline: 1.7690x; 1.7690x over previous
//
#include <hip/hip_runtime.h>

// EKF_v2: B=16384, N=128, DX=5, DZ=2.
// R4 compute arithmetic, but LDS-pipe offload:
//  - weights via UNIFORM global reads -> scalar s_load (K$), pw2^T packed in d_ws
//  - encoding/y/out via VMEM (L1), no LDS staging
//  - only state input staged in LDS (coalesced float4 -> strided reads)
// One block = 4 batches, 128 threads, 4 particles/thread.

#define NBPB 4
#define WSJ 32  // floats per packed j-block (128 B aligned)

__global__ __launch_bounds__(64) void pack_w(
    const float* __restrict__ pw2, const float* __restrict__ pb2,
    const float* __restrict__ pw3, float* __restrict__ wp)
{
    // wp[j*32 + k] = pw2[k][j] (k<16); [16]=pb2[j]; [17]=pw3[2j]; [18]=pw3[2j+1]
    for (int idx = threadIdx.x; idx < 32 * 19; idx += 64) {
        int j = idx / 19, r = idx % 19;
        float v;
        if (r < 16)      v = pw2[r * 32 + j];
        else if (r == 16) v = pb2[j];
        else             v = pw3[2 * j + (r - 17)];
        wp[j * WSJ + r] = v;
    }
}

__global__ __launch_bounds__(128) void ekf_fused(
    const float* __restrict__ state_old,  // (B,128,5)
    const float* __restrict__ y_obs,      // (B,128,2)
    const float* __restrict__ encoding,   // (B,128)
    const float* __restrict__ pw1,        // (2,16)
    const float* __restrict__ pb1,        // (16)
    const float* __restrict__ pb3,        // (2)
    const float* __restrict__ nw1,        // (128,32)
    const float* __restrict__ nb1,        // (32)
    const float* __restrict__ nw2,        // (32,2)
    const float* __restrict__ nb2,        // (2)
    const float* __restrict__ lob,        // (2)
    const float* __restrict__ fob,        // (2)
    const float* __restrict__ wp,         // packed pw2t|pb2|pw3 (32 x 32 floats)
    float* __restrict__ out)              // (B,128,5)
{
    __shared__ __align__(16) float s_state[NBPB * 640];

    const int t = threadIdx.x;
    const int base = blockIdx.x * NBPB;

    // ---- stage state (coalesced float4) ----
    {
        const float4* src = (const float4*)(state_old + (size_t)base * 640);
        float4* dst = (float4*)s_state;
        #pragma unroll
        for (int i = t; i < 640; i += 128) dst[i] = src[i];
    }
    __syncthreads();

    const int g = t >> 5;     // batch within block
    const int j32 = t & 31;   // lane within batch group
    const size_t b = (size_t)base + g;

    // ---- noise MLP: 4 independent chains; enc via float4 VMEM, nw1 coalesced ----
    float diag0, diag1;
    {
        const float4* eg4 = (const float4*)(encoding + b * 128);
        const float* w = nw1 + j32;
        float a0 = 0.0f, a1 = 0.0f, a2 = 0.0f, a3 = 0.0f;
        #pragma unroll 8
        for (int kk = 0; kk < 32; ++kk) {
            float4 e4 = eg4[kk];
            a0 = fmaf(e4.x, w[(4 * kk + 0) * 32], a0);
            a1 = fmaf(e4.y, w[(4 * kk + 1) * 32], a1);
            a2 = fmaf(e4.z, w[(4 * kk + 2) * 32], a2);
            a3 = fmaf(e4.w, w[(4 * kk + 3) * 32], a3);
        }
        float acc = ((a0 + a1) + (a2 + a3)) + nb1[j32];
        float h = fmaxf(acc, 0.0f);
        float d0 = h * nw2[2 * j32 + 0];
        float d1 = h * nw2[2 * j32 + 1];
        #pragma unroll
        for (int off = 1; off < 32; off <<= 1) {
            d0 += __shfl_xor(d0, off, 64);
            d1 += __shfl_xor(d1, off, 64);
        }
        float e0 = d0 + nb2[0] + lob[0];
        float e1 = d1 + nb2[1] + lob[1];
        diag0 = fmaf(e0, e0, fob[0]);
        diag1 = fmaf(e1, e1, fob[1]);
    }

    // ---- process model: 4 particles/thread; pw1/pb1 uniform -> s_load ----
    float xp[4][5];
    float h1[4][16];
    #pragma unroll
    for (int m = 0; m < 4; ++m) {
        const float* s = s_state + g * 640 + (j32 + 32 * m) * 5;
        float s0 = s[0], s1 = s[1], s2 = s[2], v = s[3], td = s[4];
        float theta = s2 + td;
        float sn = __sinf(theta);
        float cs = __cosf(theta);
        xp[m][0] = fmaf(v, sn, s0);
        xp[m][1] = fmaf(v, cs, s1);
        xp[m][2] = theta;
        xp[m][3] = v;
        xp[m][4] = td;
        #pragma unroll
        for (int q = 0; q < 16; ++q)
            h1[m][q] = fmaxf(0.0f, fmaf(v, pw1[q], fmaf(td, pw1[16 + q], pb1[q])));
    }

    // ---- layers 2+3 fused; weights via uniform s_load from packed wp ----
    float o3[4], o4[4];
    #pragma unroll
    for (int m = 0; m < 4; ++m) { o3[m] = 0.0f; o4[m] = 0.0f; }
    #pragma unroll
    for (int j = 0; j < 32; ++j) {
        const float* wj = wp + j * WSJ; // uniform, 128-B aligned block
        float acc[4];
        #pragma unroll
        for (int m = 0; m < 4; ++m) acc[m] = wj[16]; // pb2[j]
        #pragma unroll
        for (int k = 0; k < 16; ++k) {
            float wk = wj[k];
            #pragma unroll
            for (int m = 0; m < 4; ++m)
                acc[m] = fmaf(h1[m][k], wk, acc[m]);
        }
        float w30 = wj[17], w31 = wj[18];
        #pragma unroll
        for (int m = 0; m < 4; ++m) {
            float r = fmaxf(acc[m], 0.0f);
            o3[m] = fmaf(r, w30, o3[m]);
            o4[m] = fmaf(r, w31, o4[m]);
        }
    }
    #pragma unroll
    for (int m = 0; m < 4; ++m) {
        xp[m][3] += o3[m] + pb3[0];
        xp[m][4] += o4[m] + pb3[1];
    }

    // ---- per-batch means (butterfly over 32 lanes) ----
    float mean[5];
    #pragma unroll
    for (int i = 0; i < 5; ++i) {
        float ps = (xp[0][i] + xp[1][i]) + (xp[2][i] + xp[3][i]);
        #pragma unroll
        for (int off = 1; off < 32; off <<= 1) ps += __shfl_xor(ps, off, 64);
        mean[i] = ps * 0.0078125f; // /128 exact
    }

    float A[4][5];
    #pragma unroll
    for (int m = 0; m < 4; ++m)
        #pragma unroll
        for (int i = 0; i < 5; ++i) A[m][i] = xp[m][i] - mean[i];

    // ---- cross-moments (9 chains; S[4][0] == S[3][1] by symmetry) ----
    float S[5][2];
    #pragma unroll
    for (int i = 0; i < 5; ++i) {
        #pragma unroll
        for (int z = 0; z < 2; ++z) {
            if (i == 4 && z == 0) continue; // filled from S[3][1]
            float ps = (A[0][i] * A[0][3 + z] + A[1][i] * A[1][3 + z])
                     + (A[2][i] * A[2][3 + z] + A[3][i] * A[3][3 + z]);
            #pragma unroll
            for (int off = 1; off < 32; off <<= 1) ps += __shfl_xor(ps, off, 64);
            S[i][z] = ps;
        }
    }
    S[4][0] = S[3][1];

    // ---- 2x2 solve: Kt = Pzz^{-1} @ Pxz^T ----
    const float inv_denom = 1.0f / 127.0f;
    float p00 = fmaf(S[3][0], inv_denom, diag0);
    float p01 = S[3][1] * inv_denom;
    float p10 = S[4][0] * inv_denom;
    float p11 = fmaf(S[4][1], inv_denom, diag1);
    float det = p00 * p11 - p01 * p10;
    float rdet = 1.0f / det;
    float Kt0[5], Kt1[5];
    #pragma unroll
    for (int i = 0; i < 5; ++i) {
        float b0 = S[i][0] * inv_denom;
        float b1 = S[i][1] * inv_denom;
        Kt0[i] = (p11 * b0 - p01 * b1) * rdet;
        Kt1[i] = (p00 * b1 - p10 * b0) * rdet;
    }

    // ---- Kalman update: y via float2 VMEM, direct global stores ----
    #pragma unroll
    for (int m = 0; m < 4; ++m) {
        const int p = j32 + 32 * m;
        const float2 yy = *(const float2*)(y_obs + (b * 128 + (size_t)p) * 2);
        float i0 = yy.x - xp[m][3];
        float i1 = yy.y - xp[m][4];
        float* o = out + (b * 128 + (size_t)p) * 5;
        #pragma unroll
        for (int i = 0; i < 5; ++i)
            o[i] = xp[m][i] + i0 * Kt0[i] + i1 * Kt1[i];
    }
}

extern "C" void kernel_launch(void* const* d_in, const int* in_sizes, int n_in,
                              void* d_out, int out_size, void* d_ws, size_t ws_size,
                              hipStream_t stream) {
    const float* state_old = (const float*)d_in[0];
    const float* y_obs     = (const float*)d_in[1];
    const float* encoding  = (const float*)d_in[2];
    const float* pw1 = (const float*)d_in[3];
    const float* pb1 = (const float*)d_in[4];
    const float* pw2 = (const float*)d_in[5];
    const float* pb2 = (const float*)d_in[6];
    const float* pw3 = (const float*)d_in[7];
    const float* pb3 = (const float*)d_in[8];
    const float* nw1 = (const float*)d_in[9];
    const float* nb1 = (const float*)d_in[10];
    const float* nw2 = (const float*)d_in[11];
    const float* nb2 = (const float*)d_in[12];
    const float* lob = (const float*)d_in[13];
    const float* fob = (const float*)d_in[14];
    float* out = (float*)d_out;
    float* wpack = (float*)d_ws; // 32*32*4 = 4096 B

    hipLaunchKernelGGL(pack_w, dim3(1), dim3(64), 0, stream, pw2, pb2, pw3, wpack);

    const int B = 16384;
    dim3 grid(B / NBPB);
    dim3 block(128);
    hipLaunchKernelGGL(ekf_fused, grid, block, 0, stream,
                       state_old, y_obs, encoding,
                       pw1, pb1, pb3,
                       nw1, nb1, nw2, nb2, lob, fob, wpack, out);
}